// Round 13
// baseline (369.068 us; speedup 1.0000x reference)
//
#include <hip/hip_runtime.h>

// Problem constants
#define S_  2048
#define D_  1024
#define H_  16
#define B_  4
#define NT  32     // q-tiles per persistent block

typedef __attribute__((ext_vector_type(8))) short short8;
typedef __attribute__((ext_vector_type(4))) float f32x4;

__device__ __forceinline__ unsigned short f2bf(float f) {
  unsigned int u = __float_as_uint(f);
  u += 0x7fffu + ((u >> 16) & 1u);      // round-to-nearest-even
  return (unsigned short)(u >> 16);
}
__device__ __forceinline__ unsigned int pack2(float a, float b) {
  return (unsigned int)f2bf(a) | ((unsigned int)f2bf(b) << 16);
}
__device__ __forceinline__ float h2f(unsigned int u, int shft) {
  unsigned short hs = (unsigned short)(u >> shft);
  return (float)__builtin_bit_cast(_Float16, hs);
}

// Barrier draining ONLY LDS ops: nontemporal attn stores and global loads
// stay in flight across it (store queue is never drained mid-kernel).
__device__ __forceinline__ void bar_lgkm() {
  asm volatile("s_waitcnt lgkmcnt(0)" ::: "memory");
  __builtin_amdgcn_s_barrier();
}

// 0.125 (1/sqrt(DK)) * log2(e): use exp2 (native v_exp_f32)
#define SCL   0.18033688011112042f
#define EBIAS 12.0f   // keeps e' in fp16 range; cancels in softmax (validated R2/R8-R12)

// ---------------------------------------------------------------------------
// x (B,S,D) f32 -> xh (B,H,S,64) bf16 head-major (256 KB contiguous per bh).
// ---------------------------------------------------------------------------
__global__ __launch_bounds__(256) void xcvt(const float* __restrict__ x,
                                            unsigned short* __restrict__ xh) {
  const int n = blockIdx.x;
  const int bh = n >> 5, chunk = n & 31;
  const int b = bh >> 4, h = bh & 15;
  const int r = threadIdx.x >> 2, cg = threadIdx.x & 3;
  const int srow = chunk * 64 + r;
  const float* src = x + ((size_t)b * S_ + srow) * D_ + h * 64 + cg * 16;
  float4 v0 = ((const float4*)src)[0];
  float4 v1 = ((const float4*)src)[1];
  float4 v2 = ((const float4*)src)[2];
  float4 v3 = ((const float4*)src)[3];
  uint4 w0, w1;
  w0.x = pack2(v0.x, v0.y); w0.y = pack2(v0.z, v0.w);
  w0.z = pack2(v1.x, v1.y); w0.w = pack2(v1.z, v1.w);
  w1.x = pack2(v2.x, v2.y); w1.y = pack2(v2.z, v2.w);
  w1.z = pack2(v3.x, v3.y); w1.w = pack2(v3.z, v3.w);
  unsigned short* dst = xh + ((size_t)bh * S_ + srow) * 64 + cg * 16;
  *(uint4*)dst = w0;
  *(uint4*)(dst + 8) = w1;
}

// ---------------------------------------------------------------------------
// Persistent role-unified pipelined attention.
// grid = 256 blocks (1/CU, LDS ~132 KB), 512 thr = 8 waves (2/SIMD).
// Per tile ti, fully-unrolled i-loop (i=0..15): EVERY wave computes key tile
// kt = i*8+wv of tile ti (B-frags direct from L2-resident xh; MFMA+exp ->
// ebuf[ti&1]) AND writes slice i (128 cols x 16 rows) of tile ti-1 from
// ebuf[(ti-1)&1] as 512B-per-row contiguous nt stores. All 8 waves issue
// stores (2x R12's in-flight depth); stores spread uniformly through the
// kernel; compute hides under the per-CU HBM write pace. Zero intra-tile
// barriers; 2 lgkm-only barriers per tile (stores never drained).
// Epilogue: rowsum -> invbuf[ti&1]; colsum of tile ti -> fp16 cpart.
// Block n: xcd=n&7, bh=((n>>3)>>2)*8+xcd, q0=((n>>3)&3)*32.
// ---------------------------------------------------------------------------
__global__ __launch_bounds__(512, 1) void attn_fused(
    const unsigned short* __restrict__ xh, const int* __restrict__ sl32,
    float* __restrict__ attn, unsigned int* __restrict__ cpart)
{
  __shared__ __align__(16) unsigned int ebuf[2][8][2048];   // 128 KB e' pairs
  __shared__ float wbuf[128];
  __shared__ float invbuf[2][16];

  const int n    = blockIdx.x;
  const int xcd  = n & 7;
  const int j    = n >> 3;                 // 0..31 per XCD
  const int bh   = (j >> 2) * 8 + xcd;     // 8 bh-slices per XCD
  const int q0   = (j & 3) * NT;           // this block's q-tile range
  const int b    = bh >> 4;
  const int tid  = threadIdx.x;
  const int wv   = tid >> 6;               // 0..7
  const int lane = tid & 63;
  const int lo   = lane & 15;
  const int g    = lane >> 4;

  // seq_lens dtype auto-detect (values >= 1024 -> int64 layout has word1==0)
  const bool is64 = (sl32[1] == 0);
  const int seqlen = is64 ? sl32[2 * b] : sl32[b];

  const unsigned short* xk = xh + (size_t)bh * S_ * 64;

  // compute persona
  const int sA = ((g * 2) & 6) << 2;       // ebuf col swizzle {0,8,16,24}
  // writer persona
  const int row_w = tid >> 5;              // 0..15
  const int cu    = tid & 31;              // 0..31 (4-col unit)
  const int r2w = row_w >> 1, shw = (row_w & 1) * 16, sw2 = (r2w & 6) << 2;
  // colsum persona
  const int c0 = tid * 4;                  // 4 cols per thread

  for (int ti = 0; ti <= NT; ++ti) {
    unsigned int (*eb)[2048] = ebuf[ti & 1];                 // current tile
    const unsigned int (*ebp)[2048] = ebuf[(ti + 1) & 1];    // == (ti-1)&1
    const bool has_c = ti < NT;
    const bool has_w = ti > 0;

    short8 aq0 = {}, aq1 = {};
    if (has_c) {
      const int qt = q0 + ti;
      aq0 = *(const short8*)(xk + (size_t)(qt * 16 + lo) * 64 + g * 8);
      aq1 = *(const short8*)(xk + (size_t)(qt * 16 + lo) * 64 + g * 8 + 32);
    }
    float r0 = 0.f, r1 = 0.f, r2s = 0.f, r3 = 0.f;
    const float vr = has_w ? invbuf[(ti + 1) & 1][row_w] : 0.f;
    float* prow = attn + (size_t)bh * S_ * S_ +
                  (size_t)((q0 + ti - 1) * 16 + row_w) * S_;

#pragma unroll
    for (int i = 0; i < 16; ++i) {
      if (has_c) {
        const int kt = i * 8 + wv;
        const int kg = kt * 16 + lo;       // B-frag key row
        const unsigned short* kp = xk + (size_t)kg * 64 + g * 8;
        short8 b0 = *(const short8*)kp;
        short8 b1 = *(const short8*)(kp + 32);
        f32x4 acc = {0.f, 0.f, 0.f, 0.f};
        acc = __builtin_amdgcn_mfma_f32_16x16x32_bf16(aq0, b0, acc, 0, 0, 0);
        acc = __builtin_amdgcn_mfma_f32_16x16x32_bf16(aq1, b1, acc, 0, 0, 0);
        const bool valid = kg < seqlen;
        float e0 = valid ? exp2f(acc[0] * SCL - EBIAS) : 0.f;
        float e1 = valid ? exp2f(acc[1] * SCL - EBIAS) : 0.f;
        float e2 = valid ? exp2f(acc[2] * SCL - EBIAS) : 0.f;
        float e3 = valid ? exp2f(acc[3] * SCL - EBIAS) : 0.f;
        r0 += e0; r1 += e1; r2s += e2; r3 += e3;
        eb[g * 2][kg ^ sA] =
            __builtin_bit_cast(unsigned int, __builtin_amdgcn_cvt_pkrtz(e0, e1));
        eb[g * 2 + 1][kg ^ sA] =
            __builtin_bit_cast(unsigned int, __builtin_amdgcn_cvt_pkrtz(e2, e3));
      }
      if (has_w) {
        const int col0 = i * 128 + cu * 4;
        uint4 u = *(const uint4*)&ebp[r2w][col0 ^ sw2];
        f32x4 v = {h2f(u.x, shw) * vr, h2f(u.y, shw) * vr,
                   h2f(u.z, shw) * vr, h2f(u.w, shw) * vr};
        __builtin_nontemporal_store(v, (f32x4*)(prow + col0));
      }
    }

    // ---------------- epilogue: rowsum -> invbuf; colsum(ti) ----------------
    if (has_c) {
      float rs[4] = {r0, r1, r2s, r3};
#pragma unroll
      for (int r4 = 0; r4 < 4; ++r4) {
        float v = rs[r4];
        v += __shfl_xor(v, 1);
        v += __shfl_xor(v, 2);
        v += __shfl_xor(v, 4);
        v += __shfl_xor(v, 8);
        if (lo == 0) wbuf[wv * 16 + g * 4 + r4] = v;
      }
    }
    bar_lgkm();                       // B1: ebuf[cur] + wbuf complete
    if (has_c && tid < 16) {
      float s = 0.f;
#pragma unroll
      for (int w8 = 0; w8 < 8; ++w8) s += wbuf[w8 * 16 + tid];
      invbuf[ti & 1][tid] = 1.0f / s;
    }
    bar_lgkm();                       // B2: invbuf[cur] published
    if (has_c) {
      const float* ivc = invbuf[ti & 1];
      float a0 = 0.f, a1 = 0.f, a2 = 0.f, a3 = 0.f;
#pragma unroll
      for (int r2 = 0; r2 < 8; ++r2) {
        const int s = (r2 & 6) << 2;
        const uint4 u = *(const uint4*)&eb[r2][c0 ^ s];
        const float i0 = ivc[2 * r2], i1 = ivc[2 * r2 + 1];
        a0 += h2f(u.x, 0) * i0 + h2f(u.x, 16) * i1;
        a1 += h2f(u.y, 0) * i0 + h2f(u.y, 16) * i1;
        a2 += h2f(u.z, 0) * i0 + h2f(u.z, 16) * i1;
        a3 += h2f(u.w, 0) * i0 + h2f(u.w, 16) * i1;
      }
      uint2 w;
      w.x = __builtin_bit_cast(unsigned int, __builtin_amdgcn_cvt_pkrtz(a0, a1));
      w.y = __builtin_bit_cast(unsigned int, __builtin_amdgcn_cvt_pkrtz(a2, a3));
      *(uint2*)&cpart[(size_t)(bh * 128 + q0 + ti) * 1024 + tid * 2] = w;
    }
    // no barrier needed: next tile's compute writes ebuf[(ti+1)&1] (disjoint
    // from colsum's eb reads); its writers read eb (read-read) and
    // invbuf[ti&1] (published at B2). Barrier instances stay matched.
  }
}

// Fused creduce + csum_k:
// phase 1: c[k] = sum over 128 q-tiles of fp16 cpart  (k in this oct)
// phase 2: csump[oct][bh][d] = sum over oct's 256 keys of c[k] * xh[bh][k][d]
__global__ __launch_bounds__(256) void csum2(const unsigned int* __restrict__ cpart,
                                             const unsigned short* __restrict__ xh,
                                             float* __restrict__ csump) {
  __shared__ float csh[256];
  __shared__ float part[4][64];
  const int bh = blockIdx.x >> 3, oct = blockIdx.x & 7;
  const int t = threadIdx.x;
  {
    const int k = oct * 256 + t;
    const unsigned short* cp =
        (const unsigned short*)cpart + (size_t)bh * 128 * 2048 + k;
    float s = 0.f;
#pragma unroll 8
    for (int q = 0; q < 128; ++q)
      s += (float)__builtin_bit_cast(_Float16, cp[(size_t)q * 2048]);
    csh[t] = s;
  }
  __syncthreads();
  const int seg = t >> 6, d = t & 63;
  const unsigned short* xb = xh + (size_t)bh * S_ * 64 + d;
  const int k0 = oct * 256 + seg * 64;
  float acc = 0.f;
#pragma unroll 4
  for (int kk = 0; kk < 64; ++kk) {
    float xv = __uint_as_float((unsigned int)xb[(size_t)(k0 + kk) * 64] << 16);
    acc += csh[seg * 64 + kk] * xv;
  }
  part[seg][d] = acc;
  __syncthreads();
  if (t < 64)
    csump[((size_t)oct * 64 + bh) * 64 + d] =
        part[0][d] + part[1][d] + part[2][d] + part[3][d];
}

// out0[b][d] = sum_e csum[b][e] * W[d][e] + S * bias[d], csum = sum of octants
__global__ __launch_bounds__(256) void proj_k(const float* __restrict__ csump,
                                              const float* __restrict__ W,
                                              const float* __restrict__ bias,
                                              float* __restrict__ out0) {
  const int idx = blockIdx.x * 4 + (threadIdx.x >> 6); // (b,d) pair per wave
  const int b = idx >> 10, d = idx & 1023;
  const int lane = threadIdx.x & 63;
  const float* wr = W + (size_t)d * D_;
  float acc = 0.f;
#pragma unroll
  for (int e = 0; e < 16; ++e) {
    const int ei = lane + e * 64;            // e index within D
    const int bhh = b * 16 + (ei >> 6);      // bh of this e
    const int dd = ei & 63;
    float cv = 0.f;
#pragma unroll
    for (int oct = 0; oct < 8; ++oct)
      cv += csump[((size_t)oct * 64 + bhh) * 64 + dd];
    acc += cv * wr[ei];
  }
  acc += __shfl_xor(acc, 32);
  acc += __shfl_xor(acc, 16);
  acc += __shfl_xor(acc, 8);
  acc += __shfl_xor(acc, 4);
  acc += __shfl_xor(acc, 2);
  acc += __shfl_xor(acc, 1);
  if (lane == 0) out0[idx] = acc + 2048.0f * bias[d];
}

extern "C" void kernel_launch(void* const* d_in, const int* in_sizes, int n_in,
                              void* d_out, int out_size, void* d_ws, size_t ws_size,
                              hipStream_t stream) {
  const float* x    = (const float*)d_in[0];
  const int*   sl   = (const int*)d_in[1];
  const float* W    = (const float*)d_in[2];
  const float* bias = (const float*)d_in[3];

  float* out0 = (float*)d_out;
  float* attn = out0 + B_ * D_;

  unsigned int* cpart = (unsigned int*)d_ws;                // 64*128*1024 u32 = 33.5 MB
  float* csump = (float*)(cpart + (size_t)64 * 128 * 1024); // 8*64*64 f32 = 128 KB
  unsigned short* xh = (unsigned short*)(csump + 8 * 64 * 64); // bf16, 16 MB

  hipLaunchKernelGGL(xcvt,       dim3(2048), dim3(256), 0, stream, x, xh);
  hipLaunchKernelGGL(attn_fused, dim3(256),  dim3(512), 0, stream, xh, sl, attn, cpart);
  hipLaunchKernelGGL(csum2,      dim3(512),  dim3(256), 0, stream, cpart, xh, csump);
  hipLaunchKernelGGL(proj_k,     dim3(1024), dim3(256), 0, stream, csump, W, bias, out0);
}

// Round 14
// 344.654 us; speedup vs baseline: 1.0708x; 1.0708x over previous
//
#include <hip/hip_runtime.h>

// Problem constants
#define S_  2048
#define D_  1024
#define H_  16
#define B_  4
#define NT  32     // q-tiles per persistent block

typedef __attribute__((ext_vector_type(8))) short short8;
typedef __attribute__((ext_vector_type(4))) float f32x4;

__device__ __forceinline__ unsigned short f2bf(float f) {
  unsigned int u = __float_as_uint(f);
  u += 0x7fffu + ((u >> 16) & 1u);      // round-to-nearest-even
  return (unsigned short)(u >> 16);
}
__device__ __forceinline__ unsigned int pack2(float a, float b) {
  return (unsigned int)f2bf(a) | ((unsigned int)f2bf(b) << 16);
}
__device__ __forceinline__ float h2f(unsigned int u, int shft) {
  unsigned short hs = (unsigned short)(u >> shft);
  return (float)__builtin_bit_cast(_Float16, hs);
}

// Barrier draining ONLY LDS ops: writers' nontemporal stores and computes'
// global loads stay in flight across it.
__device__ __forceinline__ void bar_lgkm() {
  asm volatile("s_waitcnt lgkmcnt(0)" ::: "memory");
  __builtin_amdgcn_s_barrier();
}

// 0.125 (1/sqrt(DK)) * log2(e): use exp2 (native v_exp_f32)
#define SCL   0.18033688011112042f
#define EBIAS 12.0f   // keeps e' in fp16 range; cancels in softmax (validated R2/R8-R13)

// ---------------------------------------------------------------------------
// x (B,S,D) f32 -> xh (B,H,S,64) bf16 head-major (256 KB contiguous per bh).
// ---------------------------------------------------------------------------
__global__ __launch_bounds__(256) void xcvt(const float* __restrict__ x,
                                            unsigned short* __restrict__ xh) {
  const int n = blockIdx.x;
  const int bh = n >> 5, chunk = n & 31;
  const int b = bh >> 4, h = bh & 15;
  const int r = threadIdx.x >> 2, cg = threadIdx.x & 3;
  const int srow = chunk * 64 + r;
  const float* src = x + ((size_t)b * S_ + srow) * D_ + h * 64 + cg * 16;
  float4 v0 = ((const float4*)src)[0];
  float4 v1 = ((const float4*)src)[1];
  float4 v2 = ((const float4*)src)[2];
  float4 v3 = ((const float4*)src)[3];
  uint4 w0, w1;
  w0.x = pack2(v0.x, v0.y); w0.y = pack2(v0.z, v0.w);
  w0.z = pack2(v1.x, v1.y); w0.w = pack2(v1.z, v1.w);
  w1.x = pack2(v2.x, v2.y); w1.y = pack2(v2.z, v2.w);
  w1.z = pack2(v3.x, v3.y); w1.w = pack2(v3.z, v3.w);
  unsigned short* dst = xh + ((size_t)bh * S_ + srow) * 64 + cg * 16;
  *(uint4*)dst = w0;
  *(uint4*)(dst + 8) = w1;
}

// ---------------------------------------------------------------------------
// Persistent producer/consumer attention, 8 compute + 8 writer waves.
// grid = 256 blocks (1/CU, LDS ~129 KB), 1024 thr = 16 waves (4/SIMD).
// Waves 0-7 (compute): per tile ti, wave w computes key tiles kt = i*8+w,
//   B-frags DIRECT from L2-resident xh (pure-load stream: no stores ->
//   no vmcnt coupling), MFMA+exp -> ebuf[ti&1] packed fp16 row-pairs.
// Waves 8-15 (writers): stream tile ti-1 from ebuf[(ti-1)&1] as contiguous
//   nt stores (512B per half-wave) -- 8 dedicated storing waves/CU is the
//   Little's-law requirement for the ~26 GB/s/CU HBM write share. Writers
//   also do colsum(ti-1) -> fp16 cpart.
// 2 lgkm-only barriers per tile; the store queue is NEVER drained.
// Block n: xcd=n&7, bh=((n>>3)>>2)*8+xcd, q0=((n>>3)&3)*32.
// ---------------------------------------------------------------------------
__global__ __launch_bounds__(1024, 1) void attn_fused(
    const unsigned short* __restrict__ xh, const int* __restrict__ sl32,
    float* __restrict__ attn, unsigned int* __restrict__ cpart)
{
  __shared__ __align__(16) unsigned int ebuf[2][8][2048];   // 128 KB e' pairs
  __shared__ float wbuf[128];
  __shared__ float invbuf[2][16];

  const int n    = blockIdx.x;
  const int xcd  = n & 7;
  const int j    = n >> 3;                 // 0..31 per XCD
  const int bh   = (j >> 2) * 8 + xcd;     // 8 bh-slices per XCD
  const int q0   = (j & 3) * NT;           // this block's q-tile range
  const int b    = bh >> 4;
  const int tid  = threadIdx.x;
  const int role = tid >> 9;               // 0: compute (waves 0-7), 1: writers
  const int ctid = tid & 511;
  const int cwv  = ctid >> 6;              // compute wave 0..7
  const int lane = ctid & 63;
  const int lo   = lane & 15;
  const int g    = lane >> 4;

  // seq_lens dtype auto-detect (values >= 1024 -> int64 layout has word1==0)
  const bool is64 = (sl32[1] == 0);
  const int seqlen = is64 ? sl32[2 * b] : sl32[b];

  const unsigned short* xk = xh + (size_t)bh * S_ * 64;

  // compute persona
  const int sA = ((g * 2) & 6) << 2;       // ebuf col swizzle {0,8,16,24}
  // writer persona (ctid = 0..511)
  const int row_w = ctid >> 5;             // 0..15
  const int cu    = ctid & 31;             // 4-col unit within 128-col slice
  const int r2w = row_w >> 1, shw = (row_w & 1) * 16, sw2 = (r2w & 6) << 2;

  for (int ti = 0; ti <= NT; ++ti) {
    unsigned int (*eb)[2048] = ebuf[ti & 1];                 // current tile
    const unsigned int (*ebp)[2048] = ebuf[(ti + 1) & 1];    // == (ti-1)&1

    if (role == 0) {
      // ---------------- compute tile ti ----------------
      if (ti < NT) {
        const int qt = q0 + ti;
        short8 aq0 = *(const short8*)(xk + (size_t)(qt * 16 + lo) * 64 + g * 8);
        short8 aq1 = *(const short8*)(xk + (size_t)(qt * 16 + lo) * 64 + g * 8 + 32);
        float r0 = 0.f, r1 = 0.f, r2s = 0.f, r3 = 0.f;
#pragma unroll 4
        for (int i = 0; i < 16; ++i) {
          const int kt = i * 8 + cwv;
          const int kg = kt * 16 + lo;     // B-frag key row
          const unsigned short* kp = xk + (size_t)kg * 64 + g * 8;
          short8 b0 = *(const short8*)kp;
          short8 b1 = *(const short8*)(kp + 32);
          f32x4 acc = {0.f, 0.f, 0.f, 0.f};
          acc = __builtin_amdgcn_mfma_f32_16x16x32_bf16(aq0, b0, acc, 0, 0, 0);
          acc = __builtin_amdgcn_mfma_f32_16x16x32_bf16(aq1, b1, acc, 0, 0, 0);
          const bool valid = kg < seqlen;
          float e0 = valid ? exp2f(acc[0] * SCL - EBIAS) : 0.f;
          float e1 = valid ? exp2f(acc[1] * SCL - EBIAS) : 0.f;
          float e2 = valid ? exp2f(acc[2] * SCL - EBIAS) : 0.f;
          float e3 = valid ? exp2f(acc[3] * SCL - EBIAS) : 0.f;
          r0 += e0; r1 += e1; r2s += e2; r3 += e3;
          eb[g * 2][kg ^ sA] =
              __builtin_bit_cast(unsigned int, __builtin_amdgcn_cvt_pkrtz(e0, e1));
          eb[g * 2 + 1][kg ^ sA] =
              __builtin_bit_cast(unsigned int, __builtin_amdgcn_cvt_pkrtz(e2, e3));
        }
        float rs[4] = {r0, r1, r2s, r3};
#pragma unroll
        for (int r4 = 0; r4 < 4; ++r4) {
          float v = rs[r4];
          v += __shfl_xor(v, 1);
          v += __shfl_xor(v, 2);
          v += __shfl_xor(v, 4);
          v += __shfl_xor(v, 8);
          if (lo == 0) wbuf[cwv * 16 + g * 4 + r4] = v;
        }
      }
    } else if (ti > 0) {
      // ---------------- writers: stream tile ti-1 ----------------
      const float* ivp = invbuf[(ti - 1) & 1];
      const float vr = ivp[row_w];
      float* prow = attn + (size_t)bh * S_ * S_ +
                    (size_t)((q0 + ti - 1) * 16 + row_w) * S_;
#pragma unroll
      for (int i = 0; i < 16; ++i) {
        const int col0 = i * 128 + cu * 4;
        uint4 u = *(const uint4*)&ebp[r2w][col0 ^ sw2];
        f32x4 v = {h2f(u.x, shw) * vr, h2f(u.y, shw) * vr,
                   h2f(u.z, shw) * vr, h2f(u.w, shw) * vr};
        __builtin_nontemporal_store(v, (f32x4*)(prow + col0));
      }
      // colsum of tile ti-1 -> fp16 cpart (first 256 writer threads)
      if (ctid < 256) {
        const int c0 = ctid * 8;
        float a0 = 0.f, a1 = 0.f, a2 = 0.f, a3 = 0.f;
        float a4 = 0.f, a5 = 0.f, a6 = 0.f, a7 = 0.f;
#pragma unroll
        for (int r2 = 0; r2 < 8; ++r2) {
          const int s = (r2 & 6) << 2;
          const uint4 uA = *(const uint4*)&ebp[r2][c0 ^ s];
          const uint4 uB = *(const uint4*)&ebp[r2][(c0 ^ s) + 4];
          const float i0 = ivp[2 * r2], i1 = ivp[2 * r2 + 1];
          a0 += h2f(uA.x, 0) * i0 + h2f(uA.x, 16) * i1;
          a1 += h2f(uA.y, 0) * i0 + h2f(uA.y, 16) * i1;
          a2 += h2f(uA.z, 0) * i0 + h2f(uA.z, 16) * i1;
          a3 += h2f(uA.w, 0) * i0 + h2f(uA.w, 16) * i1;
          a4 += h2f(uB.x, 0) * i0 + h2f(uB.x, 16) * i1;
          a5 += h2f(uB.y, 0) * i0 + h2f(uB.y, 16) * i1;
          a6 += h2f(uB.z, 0) * i0 + h2f(uB.z, 16) * i1;
          a7 += h2f(uB.w, 0) * i0 + h2f(uB.w, 16) * i1;
        }
        uint4 w;
        w.x = __builtin_bit_cast(unsigned int, __builtin_amdgcn_cvt_pkrtz(a0, a1));
        w.y = __builtin_bit_cast(unsigned int, __builtin_amdgcn_cvt_pkrtz(a2, a3));
        w.z = __builtin_bit_cast(unsigned int, __builtin_amdgcn_cvt_pkrtz(a4, a5));
        w.w = __builtin_bit_cast(unsigned int, __builtin_amdgcn_cvt_pkrtz(a6, a7));
        *(uint4*)&cpart[(size_t)(bh * 128 + q0 + ti - 1) * 1024 + ctid * 4] = w;
      }
    }

    bar_lgkm();                      // S1: ebuf[cur]+wbuf done; writers done
    if (ti < NT && tid < 16) {
      float s = 0.f;
#pragma unroll
      for (int w8 = 0; w8 < 8; ++w8) s += wbuf[w8 * 16 + tid];
      invbuf[ti & 1][tid] = 1.0f / s;
    }
    bar_lgkm();                      // S2: invbuf[cur] published
  }
}

// Fused creduce + csum_k:
// phase 1: c[k] = sum over 128 q-tiles of fp16 cpart  (k in this oct)
// phase 2: csump[oct][bh][d] = sum over oct's 256 keys of c[k] * xh[bh][k][d]
__global__ __launch_bounds__(256) void csum2(const unsigned int* __restrict__ cpart,
                                             const unsigned short* __restrict__ xh,
                                             float* __restrict__ csump) {
  __shared__ float csh[256];
  __shared__ float part[4][64];
  const int bh = blockIdx.x >> 3, oct = blockIdx.x & 7;
  const int t = threadIdx.x;
  {
    const int k = oct * 256 + t;
    const unsigned short* cp =
        (const unsigned short*)cpart + (size_t)bh * 128 * 2048 + k;
    float s = 0.f;
#pragma unroll 8
    for (int q = 0; q < 128; ++q)
      s += (float)__builtin_bit_cast(_Float16, cp[(size_t)q * 2048]);
    csh[t] = s;
  }
  __syncthreads();
  const int seg = t >> 6, d = t & 63;
  const unsigned short* xb = xh + (size_t)bh * S_ * 64 + d;
  const int k0 = oct * 256 + seg * 64;
  float acc = 0.f;
#pragma unroll 4
  for (int kk = 0; kk < 64; ++kk) {
    float xv = __uint_as_float((unsigned int)xb[(size_t)(k0 + kk) * 64] << 16);
    acc += csh[seg * 64 + kk] * xv;
  }
  part[seg][d] = acc;
  __syncthreads();
  if (t < 64)
    csump[((size_t)oct * 64 + bh) * 64 + d] =
        part[0][d] + part[1][d] + part[2][d] + part[3][d];
}

// out0[b][d] = sum_e csum[b][e] * W[d][e] + S * bias[d], csum = sum of octants
__global__ __launch_bounds__(256) void proj_k(const float* __restrict__ csump,
                                              const float* __restrict__ W,
                                              const float* __restrict__ bias,
                                              float* __restrict__ out0) {
  const int idx = blockIdx.x * 4 + (threadIdx.x >> 6); // (b,d) pair per wave
  const int b = idx >> 10, d = idx & 1023;
  const int lane = threadIdx.x & 63;
  const float* wr = W + (size_t)d * D_;
  float acc = 0.f;
#pragma unroll
  for (int e = 0; e < 16; ++e) {
    const int ei = lane + e * 64;            // e index within D
    const int bhh = b * 16 + (ei >> 6);      // bh of this e
    const int dd = ei & 63;
    float cv = 0.f;
#pragma unroll
    for (int oct = 0; oct < 8; ++oct)
      cv += csump[((size_t)oct * 64 + bhh) * 64 + dd];
    acc += cv * wr[ei];
  }
  acc += __shfl_xor(acc, 32);
  acc += __shfl_xor(acc, 16);
  acc += __shfl_xor(acc, 8);
  acc += __shfl_xor(acc, 4);
  acc += __shfl_xor(acc, 2);
  acc += __shfl_xor(acc, 1);
  if (lane == 0) out0[idx] = acc + 2048.0f * bias[d];
}

extern "C" void kernel_launch(void* const* d_in, const int* in_sizes, int n_in,
                              void* d_out, int out_size, void* d_ws, size_t ws_size,
                              hipStream_t stream) {
  const float* x    = (const float*)d_in[0];
  const int*   sl   = (const int*)d_in[1];
  const float* W    = (const float*)d_in[2];
  const float* bias = (const float*)d_in[3];

  float* out0 = (float*)d_out;
  float* attn = out0 + B_ * D_;

  unsigned int* cpart = (unsigned int*)d_ws;                // 64*128*1024 u32 = 33.5 MB
  float* csump = (float*)(cpart + (size_t)64 * 128 * 1024); // 8*64*64 f32 = 128 KB
  unsigned short* xh = (unsigned short*)(csump + 8 * 64 * 64); // bf16, 16 MB

  hipLaunchKernelGGL(xcvt,       dim3(2048), dim3(256),  0, stream, x, xh);
  hipLaunchKernelGGL(attn_fused, dim3(256),  dim3(1024), 0, stream, xh, sl, attn, cpart);
  hipLaunchKernelGGL(csum2,      dim3(512),  dim3(256),  0, stream, cpart, xh, csump);
  hipLaunchKernelGGL(proj_k,     dim3(1024), dim3(256),  0, stream, csump, W, bias, out0);
}